// Round 2
// baseline (1582.828 us; speedup 1.0000x reference)
//
#include <hip/hip_runtime.h>
#include <hip/hip_bf16.h>

using bf16 = __hip_bfloat16;
using short8 = __attribute__((ext_vector_type(8))) short;
using float4v = __attribute__((ext_vector_type(4))) float;

#define BM 64
#define BN 64
#define BK 32
#define LDSP 40  // padded LDS row (shorts): 80B rows, 16B-aligned, breaks 96B-stride bank aliasing

__device__ inline short f2b(float x) {
  bf16 h = __float2bfloat16(x);
  return __builtin_bit_cast(short, h);
}

// load 8 contiguous elements at element-offset eoff; F32: convert f32->bf16
template<int F32>
__device__ inline short8 ld8e(const void* base, long eoff) {
  short8 r;
  if constexpr (F32) {
    const float* f = (const float*)base + eoff;
    #pragma unroll
    for (int i = 0; i < 8; ++i) r[i] = f2b(f[i]);
  } else {
    r = *(const short8*)((const short*)base + eoff);
  }
  return r;
}

// A flavors: 0: off=m*lda+k ; 1: off=k*lda+m (transpose: strided coalesced loads + b128 write)
//            2: off=(k/96)*9216+m*96+(k%96) (height-chunked direct)
// B flavors: 0: off=n*ldb+k ; 1: off=k*ldb+n (transpose) ; 2: chunked direct
// EPI: 0: f32 atomicAdd C[row*ldc+col]
//      1: bf16 store via LDS-bounce (full-line short8 stores); +f32 bias[glob row];
//         rows >= msplit go to Cv2 (split stacked output)
//      4: f32 x[row*ldc+col] += beta*v   (coalesced fused residual)
//      5: f32 x[row*ldc+col] = resid[same] + beta*v  (residual-from-input, full overwrite)
template<int AF, int BF, int EPI, int AF32, int BF32>
__global__ __launch_bounds__(256) void gemm_k(
    const void* __restrict__ Ag, const void* __restrict__ Bg,
    void* __restrict__ Cv, void* __restrict__ Cv2, const float* __restrict__ bias,
    const float* __restrict__ betaP, const float* __restrict__ resid,
    int M, int N, int K, int lda, int ldb, int ldc,
    long sA, long sB, long sC, int ksplit, int abdiv, int msplit, int swapxy)
{
  __shared__ __align__(16) short smem[(BM + BN) * LDSP];
  short (*As)[LDSP] = (short (*)[LDSP])smem;
  short (*Bs)[LDSP] = (short (*)[LDSP])(smem + BM * LDSP);
  const int t = threadIdx.x;
  const int lane = t & 63;
  const int wave = t >> 6;
  const int wm = (wave >> 1) * 32;
  const int wn = (wave & 1) * 32;
  const int fr = lane & 15;
  const int fq = lane >> 4;
  const int bz = blockIdx.z;
  const int batch = bz / ksplit;
  const int kc = bz - batch * ksplit;
  const int Kc = K / ksplit;
  const int k0 = kc * Kc;
  int bxi = blockIdx.x, byi = blockIdx.y;
  if (swapxy) { int tmp = bxi; bxi = byi; byi = tmp; }
  const int tm0 = byi * BM;
  const int tn0 = bxi * BN;
  const long abase = (long)(batch / abdiv) * sA;
  const long bbase = (long)batch * sB;

  float4v acc[2][2] = {};

  for (int kk = 0; kk < Kc; kk += BK) {
    const int kbase = k0 + kk;
    // ---- stage A tile: As[m][k] ----
    if constexpr (AF == 0 || AF == 2) {
      int m = t >> 2;
      int kloc = (t & 3) * 8;
      int gk = kbase + kloc;
      short8 v = {};
      if (tm0 + m < M) {
        long off;
        if constexpr (AF == 0) off = abase + (long)(tm0 + m) * lda + gk;
        else                   off = abase + (long)(gk / 96) * 9216 + (long)(tm0 + m) * 96 + (gk % 96);
        v = ld8e<AF32>(Ag, off);
      }
      *(short8*)&As[m][kloc] = v;
    } else {  // AF == 1: lane-coalesced over m; 8 strided loads over k; single b128 write
      int m = t & 63;
      int kg = (t >> 6) * 8;
      short8 v = {};
      if (tm0 + m < M) {
        #pragma unroll
        for (int j = 0; j < 8; ++j) {
          long off = abase + (long)(kbase + kg + j) * lda + tm0 + m;
          v[j] = AF32 ? f2b(((const float*)Ag)[off]) : ((const short*)Ag)[off];
        }
      }
      *(short8*)&As[m][kg] = v;
    }
    // ---- stage B tile: Bs[n][k] ----
    if constexpr (BF == 0 || BF == 2) {
      int n = t >> 2;
      int kloc = (t & 3) * 8;
      int gk = kbase + kloc;
      short8 v = {};
      if (tn0 + n < N) {
        long off;
        if constexpr (BF == 0) off = bbase + (long)(tn0 + n) * ldb + gk;
        else                   off = bbase + (long)(gk / 96) * 9216 + (long)(tn0 + n) * 96 + (gk % 96);
        v = ld8e<BF32>(Bg, off);
      }
      *(short8*)&Bs[n][kloc] = v;
    } else {  // BF == 1
      int n = t & 63;
      int kg = (t >> 6) * 8;
      short8 v = {};
      if (tn0 + n < N) {
        #pragma unroll
        for (int j = 0; j < 8; ++j) {
          long off = bbase + (long)(kbase + kg + j) * ldb + tn0 + n;
          v[j] = BF32 ? f2b(((const float*)Bg)[off]) : ((const short*)Bg)[off];
        }
      }
      *(short8*)&Bs[n][kg] = v;
    }
    __syncthreads();
    short8 af[2], bfv[2];
    #pragma unroll
    for (int i = 0; i < 2; ++i) af[i] = *(const short8*)&As[wm + i * 16 + fr][fq * 8];
    #pragma unroll
    for (int j = 0; j < 2; ++j) bfv[j] = *(const short8*)&Bs[wn + j * 16 + fr][fq * 8];
    #pragma unroll
    for (int i = 0; i < 2; ++i)
      #pragma unroll
      for (int j = 0; j < 2; ++j)
        acc[i][j] = __builtin_amdgcn_mfma_f32_16x16x32_bf16(af[i], bfv[j], acc[i][j], 0, 0, 0);
    __syncthreads();
  }

  float beta = 0.0f;
  if constexpr (EPI >= 2) beta = *betaP;
  const long cb = (long)batch * sC;

  if constexpr (EPI == 1) {
    // LDS-bounce: acc -> bf16 tile in LDS -> full-128B-line short8 stores.
    short* Cb = (short*)Cv;
    int rbase = tm0;
    if (Cv2 != nullptr && tm0 >= msplit) { Cb = (short*)Cv2; rbase = tm0 - msplit; }
    short (*Ct)[72] = (short (*)[72])smem;  // 64x72 shorts = 9216B <= 10240B, 144B rows (16B aligned)
    #pragma unroll
    for (int i = 0; i < 2; ++i)
      #pragma unroll
      for (int j = 0; j < 2; ++j)
        #pragma unroll
        for (int r = 0; r < 4; ++r) {
          int row = wm + i * 16 + fq * 4 + r;
          int col = wn + j * 16 + fr;
          float v = acc[i][j][r];
          if (bias) v += bias[tm0 + row];
          Ct[row][col] = f2b(v);
        }
    __syncthreads();
    const bool full = (tm0 + BM <= M) && (tn0 + BN <= N);
    #pragma unroll
    for (int rr = 0; rr < 2; ++rr) {
      int row = rr * 32 + (t >> 3);
      int c8 = (t & 7) * 8;
      if (full) {
        *(short8*)(Cb + cb + (long)(rbase + row) * ldc + tn0 + c8) = *(const short8*)&Ct[row][c8];
      } else if (tm0 + row < M) {
        #pragma unroll
        for (int e = 0; e < 8; ++e)
          if (tn0 + c8 + e < N)
            Cb[cb + (long)(rbase + row) * ldc + tn0 + c8 + e] = Ct[row][c8 + e];
      }
    }
  } else {
    #pragma unroll
    for (int i = 0; i < 2; ++i) {
      #pragma unroll
      for (int j = 0; j < 2; ++j) {
        #pragma unroll
        for (int r = 0; r < 4; ++r) {
          int row = tm0 + wm + i * 16 + fq * 4 + r;
          int col = tn0 + wn + j * 16 + fr;
          if (row < M && col < N) {
            float v = acc[i][j][r];
            if constexpr (EPI == 0) {
              atomicAdd((float*)Cv + cb + (long)row * ldc + col, v);
            } else if constexpr (EPI == 4) {
              float* xp = (float*)Cv;
              xp[cb + (long)row * ldc + col] += beta * v;
            } else {  // EPI == 5
              float* xp = (float*)Cv;
              long idx = cb + (long)row * ldc + col;
              xp[idx] = resid[idx] + beta * v;
            }
          }
        }
      }
    }
  }
}

// softmax over n cols; logits' = in[row][c] (+ addj[b*n+c]) (+ rowv[row]*colv[c]); out bf16
__global__ __launch_bounds__(256) void softmax_k(
    const float* __restrict__ in, short* __restrict__ out, int n, int rows,
    const float* __restrict__ addj, const float* __restrict__ rowv,
    const float* __restrict__ colv)
{
  int wave = threadIdx.x >> 6;
  int lane = threadIdx.x & 63;
  int row = blockIdx.x * 4 + wave;
  if (row >= rows) return;
  int b = row / n;
  const float* r = in + (long)row * n;
  float rv = rowv ? rowv[row] : 0.0f;
  float vals[4];
  float m = -1e30f;
  #pragma unroll
  for (int i = 0; i < 4; ++i) {
    int c = lane + i * 64;
    float v = -1e30f;
    if (c < n) {
      v = r[c];
      if (addj) v += addj[(long)b * n + c];
      if (colv) v += rv * colv[c];
    }
    vals[i] = v;
    m = fmaxf(m, v);
  }
  #pragma unroll
  for (int off = 32; off > 0; off >>= 1) m = fmaxf(m, __shfl_xor(m, off));
  float s = 0.0f;
  #pragma unroll
  for (int i = 0; i < 4; ++i) {
    int c = lane + i * 64;
    float e = (c < n) ? __expf(vals[i] - m) : 0.0f;
    vals[i] = e;
    s += e;
  }
  #pragma unroll
  for (int off = 32; off > 0; off >>= 1) s += __shfl_xor(s, off);
  float inv = 1.0f / s;
  #pragma unroll
  for (int i = 0; i < 4; ++i) {
    int c = lane + i * 64;
    if (c < n) out[(long)row * n + c] = f2b(vals[i] * inv);
  }
}

// dst[row] = sum_k bf16 src[row*rowlen+k]
__global__ __launch_bounds__(256) void sum_rows_k(
    const short* __restrict__ src, float* __restrict__ dst, int rowlen, int nrows)
{
  int wave = threadIdx.x >> 6;
  int lane = threadIdx.x & 63;
  int row = blockIdx.x * 4 + wave;
  if (row >= nrows) return;
  const short* p = src + (long)row * rowlen;
  float s = 0.0f;
  for (int k = lane; k < rowlen; k += 64)
    s += __bfloat162float(__builtin_bit_cast(bf16, p[k]));
  #pragma unroll
  for (int off = 32; off > 0; off >>= 1) s += __shfl_xor(s, off);
  if (lane == 0) dst[row] = s;
}

// wv[c] = sum_o btheta[o] * Wphi[o*256+c]
__global__ __launch_bounds__(256) void wv_k(
    const float* __restrict__ wphi, const float* __restrict__ btheta, float* __restrict__ wv)
{
  int c = threadIdx.x;
  float s = 0.0f;
  for (int o = 0; o < 256; ++o) s += btheta[o] * wphi[o * 256 + c];
  wv[c] = s;
}

// vfull[b][hw] = sum_c wv[c] * x[b][c*9216+hw]
__global__ __launch_bounds__(256) void vfull_k(
    const float* __restrict__ x, const float* __restrict__ wv, float* __restrict__ vf)
{
  long idx = (long)blockIdx.x * 256 + threadIdx.x;
  int b = (int)(idx / 9216);
  int hw = (int)(idx % 9216);
  const float* p = x + (long)b * 2359296 + hw;
  float s = 0.0f;
  for (int c = 0; c < 256; ++c) s += wv[c] * p[(long)c * 9216];
  vf[idx] = s;
}

// axis 0 (width): r[b][j]=sum_h vf[b][h*96+j]; axis 1 (height): r[b][j]=sum_w vf[b][j*96+w]
__global__ __launch_bounds__(256) void rsum_k(
    const float* __restrict__ vf, float* __restrict__ r, int axis)
{
  int idx = blockIdx.x * 256 + threadIdx.x;
  int b = idx / 96;
  int j = idx % 96;
  const float* p = vf + (long)b * 9216;
  float s = 0.0f;
  if (axis == 0) { for (int h = 0; h < 96; ++h) s += p[h * 96 + j]; }
  else           { for (int w = 0; w < 96; ++w) s += p[j * 96 + w]; }
  r[idx] = s;
}

// build stacked weights: st1 = [M(bf16, filled by gemm); Wg], st2 = [Wth; Wg]; bias1=[0;bg], bias2=[bth;bg]
__global__ __launch_bounds__(256) void fill_k(
    const float* __restrict__ wth, const float* __restrict__ wg,
    const float* __restrict__ bth, const float* __restrict__ bg,
    short* __restrict__ st1, short* __restrict__ st2,
    float* __restrict__ b1, float* __restrict__ b2)
{
  int r = blockIdx.x, c = threadIdx.x;
  if (r < 256) {
    st2[r * 256 + c] = f2b(wth[r * 256 + c]);
  } else {
    short v = f2b(wg[(r - 256) * 256 + c]);
    st1[r * 256 + c] = v;
    st2[r * 256 + c] = v;
  }
  if (r == 0) { b1[c] = 0.0f; b2[c] = bth[c]; }
  if (r == 1) { b1[256 + c] = bg[c]; b2[256 + c] = bg[c]; }
}

extern "C" void kernel_launch(void* const* d_in, const int* in_sizes, int n_in,
                              void* d_out, int out_size, void* d_ws, size_t ws_size,
                              hipStream_t stream)
{
  const long TS = 37748736L;   // 16*256*96*96
  const long BS = 2359296L;    // 256*96*96

  float* x = (float*)d_out;    // f32 state; fully written by pass-0 PV (EPI=5)
  const float* xin = (const float*)d_in[0];
  const float* wth = (const float*)d_in[1];
  const float* bth = (const float*)d_in[2];
  const float* wph = (const float*)d_in[3];
  const float* bph = (const float*)d_in[4];
  const float* wg  = (const float*)d_in[5];
  const float* bg  = (const float*)d_in[6];
  const float* beta_w = (const float*)d_in[7];
  const float* beta_h = (const float*)d_in[8];
  const float* beta_c = (const float*)d_in[9];

  // workspace layout: [bigY][bigG (fused only)][pool]
  const size_t need_fused = (size_t)4 * TS + 12u * 1024 * 1024;  // ~163.6 MB
  const bool fused = ws_size >= need_fused;

  short* bigY = (short*)d_ws;                       // bf16 Y / Theta  [16][256][9216]
  short* bigG = fused ? bigY + TS : bigY;           // bf16 G; fallback: overwrites Y after QK
  char*  pool = (char*)(bigG + TS);
  float* attf  = (float*)pool;                      // 4 MB logits (max 16*65536)
  short* attb  = (short*)(attf + 1048576);          // 2 MB bf16 softmaxed att
  float* Zf    = (float*)(attb + 1048576);          // 4 MB f32 [16,256,256]
  short* st1   = (short*)(Zf + 1048576);            // [512][256] bf16: [M; Wg]
  short* st2   = st1 + 131072;                      // [512][256] bf16: [Wth; Wg]
  float* bias1 = (float*)(st2 + 131072);            // [512]: [0; bg]
  float* bias2 = bias1 + 512;                       // [512]: [bth; bg]
  float* vfull = bias2 + 512;                       // [16,9216]
  float* rbuf  = vfull + 147456;                    // [16,96]
  float* wv    = rbuf + 1536;                       // [256]
  float* tbar  = wv + 256;                          // [16,256]

  dim3 blk(256);

  // ---- precompute: st1 rows 0-255 = M = Wtheta^T * Wphi (bf16); stacks; wv ----
  gemm_k<1,1,1,1,1><<<dim3(4,4,1), blk, 0, stream>>>(wth, wph, st1, nullptr, nullptr, nullptr, nullptr,
      256, 256, 256, 256, 256, 256, 0, 0, 0, 1, 1, 0, 0);
  fill_k<<<512, blk, 0, stream>>>(wth, wg, bth, bg, st1, st2, bias1, bias2);
  wv_k<<<1, blk, 0, stream>>>(wph, bth, wv);

  // ================= pass 0 (width), pass 1 (height) =================
  for (int pass = 0; pass < 2; ++pass) {
    const float* xs = (pass == 0) ? xin : (const float*)x;
    // [Y; G] = [M; Wg] * x (+[0; bg]) -> bigY rows<256, bigG rows>=256  (x streamed ONCE)
    if (fused) {
      gemm_k<0,1,1,0,1><<<dim3(8,144,16), blk, 0, stream>>>(st1, xs, bigY, bigG, bias1, nullptr, nullptr,
          512, 9216, 256, 256, 9216, 9216, 0, BS, BS, 1, 1, 256, 1);
    } else {
      gemm_k<0,1,1,0,1><<<dim3(4,144,16), blk, 0, stream>>>(st1, xs, bigY, nullptr, nullptr, nullptr, nullptr,
          256, 9216, 256, 256, 9216, 9216, 0, BS, BS, 1, 1, 0, 1);
    }
    // column bias r[b][j]
    vfull_k<<<576, blk, 0, stream>>>(xs, wv, vfull);
    rsum_k<<<6, blk, 0, stream>>>(vfull, rbuf, pass);
    // QK: logits[i][j] = sum_{(c,axis)} x(k,i) * Y(k,j)   (split-K 16)
    hipMemsetAsync(attf, 0, (size_t)16 * 9216 * sizeof(float), stream);
    if (pass == 0)
      gemm_k<1,1,0,1,0><<<dim3(2,2,256), blk, 0, stream>>>(xs, bigY, attf, nullptr, nullptr, nullptr, nullptr,
          96, 96, 24576, 96, 96, 96, BS, BS, 9216, 16, 1, 0, 0);
    else
      gemm_k<2,2,0,1,0><<<dim3(2,2,256), blk, 0, stream>>>(xs, bigY, attf, nullptr, nullptr, nullptr, nullptr,
          96, 96, 24576, 0, 0, 96, BS, BS, 9216, 16, 1, 0, 0);
    softmax_k<<<384, blk, 0, stream>>>(attf, attb, 96, 1536, rbuf, nullptr, nullptr);
    // fallback: G = Wg*x + bg separately (overwrites Y, now dead)
    if (!fused) {
      gemm_k<0,1,1,0,1><<<dim3(4,144,16), blk, 0, stream>>>(st1 + 65536, xs, bigG, nullptr, bias1 + 256,
          nullptr, nullptr, 256, 9216, 256, 256, 9216, 9216, 0, BS, BS, 1, 1, 0, 1);
    }
    // PV fused residual
    if (pass == 0)
      // x[b*BS + m*96 + n] = xin[...] + beta_w * sum_k G[m,k] att[n,k]  (full overwrite, no memcpy)
      gemm_k<0,0,5,0,0><<<dim3(2,384,16), blk, 0, stream>>>(bigG, attb, x, nullptr, nullptr, beta_w, xin,
          24576, 96, 96, 96, 96, 96, BS, 9216, BS, 1, 1, 0, 0);
    else
      // batched over (b,c): x += beta_h * att_b * G_{b,c}
      gemm_k<0,1,4,0,0><<<dim3(2,2,4096), blk, 0, stream>>>(attb, bigG, x, nullptr, nullptr, beta_h, nullptr,
          96, 96, 96, 96, 96, 96, 9216, 9216, 9216, 1, 256, 0, 0);
  }

  // ================= pass 2 (channel) =================
  // [Theta; G] = [Wth; Wg] * x + [bth; bg]
  if (fused) {
    gemm_k<0,1,1,0,1><<<dim3(8,144,16), blk, 0, stream>>>(st2, x, bigY, bigG, bias2, nullptr, nullptr,
        512, 9216, 256, 256, 9216, 9216, 0, BS, BS, 1, 1, 256, 1);
  } else {
    gemm_k<0,1,1,0,1><<<dim3(4,144,16), blk, 0, stream>>>(st2, x, bigY, nullptr, bias2, nullptr, nullptr,
        256, 9216, 256, 256, 9216, 9216, 0, BS, BS, 1, 1, 0, 1);
  }
  // Z[i][c] = sum_hw Theta[i,hw] * x[c,hw] (split-K 4)
  hipMemsetAsync(Zf, 0, (size_t)16 * 256 * 256 * sizeof(float), stream);
  gemm_k<0,0,0,0,1><<<dim3(4,4,64), blk, 0, stream>>>(bigY, x, Zf, nullptr, nullptr, nullptr, nullptr,
      256, 256, 9216, 9216, 9216, 256, BS, BS, 65536, 4, 1, 0, 0);
  // tbar[b][i] = sum_hw Theta[i,hw]
  sum_rows_k<<<1024, blk, 0, stream>>>(bigY, tbar, 9216, 4096);
  // L = Z * Wphi^T
  hipMemsetAsync(attf, 0, (size_t)16 * 256 * 256 * sizeof(float), stream);
  gemm_k<0,0,0,1,1><<<dim3(4,4,16), blk, 0, stream>>>(Zf, wph, attf, nullptr, nullptr, nullptr, nullptr,
      256, 256, 256, 256, 256, 256, 65536, 0, 65536, 1, 1, 0, 0);
  // softmax with rank-1 term tbar[row]*bphi[col]
  softmax_k<<<1024, blk, 0, stream>>>(attf, attb, 256, 4096, nullptr, tbar, bph);
  // fallback: G separately (overwrites Theta, now dead)
  if (!fused) {
    gemm_k<0,1,1,0,1><<<dim3(4,144,16), blk, 0, stream>>>(st1 + 65536, x, bigG, nullptr, bias1 + 256,
        nullptr, nullptr, 256, 9216, 256, 256, 9216, 9216, 0, BS, BS, 1, 1, 0, 1);
  }
  // PV: x[i,hw] += beta_c * sum_j att[i,j] G[j,hw]
  gemm_k<0,1,4,0,0><<<dim3(144,4,16), blk, 0, stream>>>(attb, bigG, x, nullptr, nullptr, beta_c, nullptr,
      256, 9216, 256, 256, 9216, 9216, 65536, BS, BS, 1, 1, 0, 0);
}

// Round 3
// 1431.716 us; speedup vs baseline: 1.1055x; 1.1055x over previous
//
#include <hip/hip_runtime.h>
#include <hip/hip_bf16.h>

using bf16 = __hip_bfloat16;
using short8 = __attribute__((ext_vector_type(8))) short;
using float4v = __attribute__((ext_vector_type(4))) float;

#define BM 64
#define BN 64
#define BK 32
#define LDSP 40  // padded LDS row (shorts): 80B rows, 16B-aligned, breaks 96B-stride bank aliasing

__device__ inline short f2b(float x) {
  bf16 h = __float2bfloat16(x);
  return __builtin_bit_cast(short, h);
}

// load 8 contiguous elements at element-offset eoff; F32: convert f32->bf16
template<int F32>
__device__ inline short8 ld8e(const void* base, long eoff) {
  short8 r;
  if constexpr (F32) {
    const float* f = (const float*)base + eoff;
    #pragma unroll
    for (int i = 0; i < 8; ++i) r[i] = f2b(f[i]);
  } else {
    r = *(const short8*)((const short*)base + eoff);
  }
  return r;
}

// A flavors: 0: off=m*lda+k ; 1: off=k*lda+m (transpose: strided coalesced loads + b128 write)
//            2: off=(k/96)*9216+m*96+(k%96) (height-chunked direct)
// B flavors: 0: off=n*ldb+k ; 1: off=k*ldb+n (transpose) ; 2: chunked direct
// EPI: 0: f32 atomicAdd C[row*ldc+col]
//      1: bf16 store via LDS-bounce (full-line short8 stores); +f32 bias[glob row];
//         rows >= msplit go to Cv2 (split stacked output)
//      4: f32 x[row*ldc+col] += beta*v   (coalesced fused residual)
//      5: f32 x[row*ldc+col] = resid[same] + beta*v  (residual-from-input, full overwrite)
// NOTE on grid order: blockIdx.x MUST iterate the N-tiles (144 of them) with M-tiles in
// blockIdx.y. Same-B-panel blocks are then 144 apart in linear ID == 0 mod 8 -> same XCD L2,
// so the big B operand (x) is fetched ~once. M-tiles-adjacent ordering round-robins the
// panel across all 8 XCD L2s (4x FETCH_SIZE measured in round 2).
template<int AF, int BF, int EPI, int AF32, int BF32>
__global__ __launch_bounds__(256) void gemm_k(
    const void* __restrict__ Ag, const void* __restrict__ Bg,
    void* __restrict__ Cv, void* __restrict__ Cv2, const float* __restrict__ bias,
    const float* __restrict__ betaP, const float* __restrict__ resid,
    int M, int N, int K, int lda, int ldb, int ldc,
    long sA, long sB, long sC, int ksplit, int abdiv, int msplit, int swapxy)
{
  __shared__ __align__(16) short smem[(BM + BN) * LDSP];
  short (*As)[LDSP] = (short (*)[LDSP])smem;
  short (*Bs)[LDSP] = (short (*)[LDSP])(smem + BM * LDSP);
  const int t = threadIdx.x;
  const int lane = t & 63;
  const int wave = t >> 6;
  const int wm = (wave >> 1) * 32;
  const int wn = (wave & 1) * 32;
  const int fr = lane & 15;
  const int fq = lane >> 4;
  const int bz = blockIdx.z;
  const int batch = bz / ksplit;
  const int kc = bz - batch * ksplit;
  const int Kc = K / ksplit;
  const int k0 = kc * Kc;
  int bxi = blockIdx.x, byi = blockIdx.y;
  if (swapxy) { int tmp = bxi; bxi = byi; byi = tmp; }
  const int tm0 = byi * BM;
  const int tn0 = bxi * BN;
  const long abase = (long)(batch / abdiv) * sA;
  const long bbase = (long)batch * sB;

  float4v acc[2][2] = {};

  for (int kk = 0; kk < Kc; kk += BK) {
    const int kbase = k0 + kk;
    // ---- stage A tile: As[m][k] ----
    if constexpr (AF == 0 || AF == 2) {
      int m = t >> 2;
      int kloc = (t & 3) * 8;
      int gk = kbase + kloc;
      short8 v = {};
      if (tm0 + m < M) {
        long off;
        if constexpr (AF == 0) off = abase + (long)(tm0 + m) * lda + gk;
        else                   off = abase + (long)(gk / 96) * 9216 + (long)(tm0 + m) * 96 + (gk % 96);
        v = ld8e<AF32>(Ag, off);
      }
      *(short8*)&As[m][kloc] = v;
    } else {  // AF == 1: lane-coalesced over m; 8 strided loads over k; single b128 write
      int m = t & 63;
      int kg = (t >> 6) * 8;
      short8 v = {};
      if (tm0 + m < M) {
        #pragma unroll
        for (int j = 0; j < 8; ++j) {
          long off = abase + (long)(kbase + kg + j) * lda + tm0 + m;
          v[j] = AF32 ? f2b(((const float*)Ag)[off]) : ((const short*)Ag)[off];
        }
      }
      *(short8*)&As[m][kg] = v;
    }
    // ---- stage B tile: Bs[n][k] ----
    if constexpr (BF == 0 || BF == 2) {
      int n = t >> 2;
      int kloc = (t & 3) * 8;
      int gk = kbase + kloc;
      short8 v = {};
      if (tn0 + n < N) {
        long off;
        if constexpr (BF == 0) off = bbase + (long)(tn0 + n) * ldb + gk;
        else                   off = bbase + (long)(gk / 96) * 9216 + (long)(tn0 + n) * 96 + (gk % 96);
        v = ld8e<BF32>(Bg, off);
      }
      *(short8*)&Bs[n][kloc] = v;
    } else {  // BF == 1
      int n = t & 63;
      int kg = (t >> 6) * 8;
      short8 v = {};
      if (tn0 + n < N) {
        #pragma unroll
        for (int j = 0; j < 8; ++j) {
          long off = bbase + (long)(kbase + kg + j) * ldb + tn0 + n;
          v[j] = BF32 ? f2b(((const float*)Bg)[off]) : ((const short*)Bg)[off];
        }
      }
      *(short8*)&Bs[n][kg] = v;
    }
    __syncthreads();
    short8 af[2], bfv[2];
    #pragma unroll
    for (int i = 0; i < 2; ++i) af[i] = *(const short8*)&As[wm + i * 16 + fr][fq * 8];
    #pragma unroll
    for (int j = 0; j < 2; ++j) bfv[j] = *(const short8*)&Bs[wn + j * 16 + fr][fq * 8];
    #pragma unroll
    for (int i = 0; i < 2; ++i)
      #pragma unroll
      for (int j = 0; j < 2; ++j)
        acc[i][j] = __builtin_amdgcn_mfma_f32_16x16x32_bf16(af[i], bfv[j], acc[i][j], 0, 0, 0);
    __syncthreads();
  }

  float beta = 0.0f;
  if constexpr (EPI >= 2) beta = *betaP;
  const long cb = (long)batch * sC;

  if constexpr (EPI == 1) {
    // LDS-bounce: acc -> bf16 tile in LDS -> full-128B-line short8 stores.
    short* Cb = (short*)Cv;
    int rbase = tm0;
    if (Cv2 != nullptr && tm0 >= msplit) { Cb = (short*)Cv2; rbase = tm0 - msplit; }
    short (*Ct)[72] = (short (*)[72])smem;  // 64x72 shorts = 9216B <= 10240B, 144B rows (16B aligned)
    #pragma unroll
    for (int i = 0; i < 2; ++i)
      #pragma unroll
      for (int j = 0; j < 2; ++j)
        #pragma unroll
        for (int r = 0; r < 4; ++r) {
          int row = wm + i * 16 + fq * 4 + r;
          int col = wn + j * 16 + fr;
          float v = acc[i][j][r];
          if (bias) v += bias[tm0 + row];
          Ct[row][col] = f2b(v);
        }
    __syncthreads();
    const bool full = (tm0 + BM <= M) && (tn0 + BN <= N);
    #pragma unroll
    for (int rr = 0; rr < 2; ++rr) {
      int row = rr * 32 + (t >> 3);
      int c8 = (t & 7) * 8;
      if (full) {
        *(short8*)(Cb + cb + (long)(rbase + row) * ldc + tn0 + c8) = *(const short8*)&Ct[row][c8];
      } else if (tm0 + row < M) {
        #pragma unroll
        for (int e = 0; e < 8; ++e)
          if (tn0 + c8 + e < N)
            Cb[cb + (long)(rbase + row) * ldc + tn0 + c8 + e] = Ct[row][c8 + e];
      }
    }
  } else {
    #pragma unroll
    for (int i = 0; i < 2; ++i) {
      #pragma unroll
      for (int j = 0; j < 2; ++j) {
        #pragma unroll
        for (int r = 0; r < 4; ++r) {
          int row = tm0 + wm + i * 16 + fq * 4 + r;
          int col = tn0 + wn + j * 16 + fr;
          if (row < M && col < N) {
            float v = acc[i][j][r];
            if constexpr (EPI == 0) {
              atomicAdd((float*)Cv + cb + (long)row * ldc + col, v);
            } else if constexpr (EPI == 4) {
              float* xp = (float*)Cv;
              xp[cb + (long)row * ldc + col] += beta * v;
            } else {  // EPI == 5
              float* xp = (float*)Cv;
              long idx = cb + (long)row * ldc + col;
              xp[idx] = resid[idx] + beta * v;
            }
          }
        }
      }
    }
  }
}

// softmax over n cols; logits' = in[row][c] (+ addj[b*n+c]) (+ rowv[row]*colv[c]); out bf16
__global__ __launch_bounds__(256) void softmax_k(
    const float* __restrict__ in, short* __restrict__ out, int n, int rows,
    const float* __restrict__ addj, const float* __restrict__ rowv,
    const float* __restrict__ colv)
{
  int wave = threadIdx.x >> 6;
  int lane = threadIdx.x & 63;
  int row = blockIdx.x * 4 + wave;
  if (row >= rows) return;
  int b = row / n;
  const float* r = in + (long)row * n;
  float rv = rowv ? rowv[row] : 0.0f;
  float vals[4];
  float m = -1e30f;
  #pragma unroll
  for (int i = 0; i < 4; ++i) {
    int c = lane + i * 64;
    float v = -1e30f;
    if (c < n) {
      v = r[c];
      if (addj) v += addj[(long)b * n + c];
      if (colv) v += rv * colv[c];
    }
    vals[i] = v;
    m = fmaxf(m, v);
  }
  #pragma unroll
  for (int off = 32; off > 0; off >>= 1) m = fmaxf(m, __shfl_xor(m, off));
  float s = 0.0f;
  #pragma unroll
  for (int i = 0; i < 4; ++i) {
    int c = lane + i * 64;
    float e = (c < n) ? __expf(vals[i] - m) : 0.0f;
    vals[i] = e;
    s += e;
  }
  #pragma unroll
  for (int off = 32; off > 0; off >>= 1) s += __shfl_xor(s, off);
  float inv = 1.0f / s;
  #pragma unroll
  for (int i = 0; i < 4; ++i) {
    int c = lane + i * 64;
    if (c < n) out[(long)row * n + c] = f2b(vals[i] * inv);
  }
}

// dst[row] = sum_k bf16 src[row*rowlen+k]
__global__ __launch_bounds__(256) void sum_rows_k(
    const short* __restrict__ src, float* __restrict__ dst, int rowlen, int nrows)
{
  int wave = threadIdx.x >> 6;
  int lane = threadIdx.x & 63;
  int row = blockIdx.x * 4 + wave;
  if (row >= nrows) return;
  const short* p = src + (long)row * rowlen;
  float s = 0.0f;
  for (int k = lane; k < rowlen; k += 64)
    s += __bfloat162float(__builtin_bit_cast(bf16, p[k]));
  #pragma unroll
  for (int off = 32; off > 0; off >>= 1) s += __shfl_xor(s, off);
  if (lane == 0) dst[row] = s;
}

// wv[c] = sum_o btheta[o] * Wphi[o*256+c]
__global__ __launch_bounds__(256) void wv_k(
    const float* __restrict__ wphi, const float* __restrict__ btheta, float* __restrict__ wv)
{
  int c = threadIdx.x;
  float s = 0.0f;
  for (int o = 0; o < 256; ++o) s += btheta[o] * wphi[o * 256 + c];
  wv[c] = s;
}

// vfull[b][hw] = sum_c wv[c] * x[b][c*9216+hw]
__global__ __launch_bounds__(256) void vfull_k(
    const float* __restrict__ x, const float* __restrict__ wv, float* __restrict__ vf)
{
  long idx = (long)blockIdx.x * 256 + threadIdx.x;
  int b = (int)(idx / 9216);
  int hw = (int)(idx % 9216);
  const float* p = x + (long)b * 2359296 + hw;
  float s = 0.0f;
  for (int c = 0; c < 256; ++c) s += wv[c] * p[(long)c * 9216];
  vf[idx] = s;
}

// axis 0 (width): r[b][j]=sum_h vf[b][h*96+j]; axis 1 (height): r[b][j]=sum_w vf[b][j*96+w]
__global__ __launch_bounds__(256) void rsum_k(
    const float* __restrict__ vf, float* __restrict__ r, int axis)
{
  int idx = blockIdx.x * 256 + threadIdx.x;
  int b = idx / 96;
  int j = idx % 96;
  const float* p = vf + (long)b * 9216;
  float s = 0.0f;
  if (axis == 0) { for (int h = 0; h < 96; ++h) s += p[h * 96 + j]; }
  else           { for (int w = 0; w < 96; ++w) s += p[j * 96 + w]; }
  r[idx] = s;
}

// build stacked weights: st1 = [M(bf16, filled by gemm); Wg], st2 = [Wth; Wg]; bias1=[0;bg], bias2=[bth;bg]
__global__ __launch_bounds__(256) void fill_k(
    const float* __restrict__ wth, const float* __restrict__ wg,
    const float* __restrict__ bth, const float* __restrict__ bg,
    short* __restrict__ st1, short* __restrict__ st2,
    float* __restrict__ b1, float* __restrict__ b2)
{
  int r = blockIdx.x, c = threadIdx.x;
  if (r < 256) {
    st2[r * 256 + c] = f2b(wth[r * 256 + c]);
  } else {
    short v = f2b(wg[(r - 256) * 256 + c]);
    st1[r * 256 + c] = v;
    st2[r * 256 + c] = v;
  }
  if (r == 0) { b1[c] = 0.0f; b2[c] = bth[c]; }
  if (r == 1) { b1[256 + c] = bg[c]; b2[256 + c] = bg[c]; }
}

extern "C" void kernel_launch(void* const* d_in, const int* in_sizes, int n_in,
                              void* d_out, int out_size, void* d_ws, size_t ws_size,
                              hipStream_t stream)
{
  const long TS = 37748736L;   // 16*256*96*96
  const long BS = 2359296L;    // 256*96*96

  float* x = (float*)d_out;    // f32 state; fully written by pass-0 PV (EPI=5)
  const float* xin = (const float*)d_in[0];
  const float* wth = (const float*)d_in[1];
  const float* bth = (const float*)d_in[2];
  const float* wph = (const float*)d_in[3];
  const float* bph = (const float*)d_in[4];
  const float* wg  = (const float*)d_in[5];
  const float* bg  = (const float*)d_in[6];
  const float* beta_w = (const float*)d_in[7];
  const float* beta_h = (const float*)d_in[8];
  const float* beta_c = (const float*)d_in[9];

  // workspace layout: [bigY][bigG (fused only)][pool]
  const size_t need_fused = (size_t)4 * TS + 12u * 1024 * 1024;  // ~163.6 MB
  const bool fused = ws_size >= need_fused;

  short* bigY = (short*)d_ws;                       // bf16 Y / Theta  [16][256][9216]
  short* bigG = fused ? bigY + TS : bigY;           // bf16 G; fallback: overwrites Y after QK
  char*  pool = (char*)(bigG + TS);
  float* attf  = (float*)pool;                      // 4 MB logits (max 16*65536)
  short* attb  = (short*)(attf + 1048576);          // 2 MB bf16 softmaxed att
  float* Zf    = (float*)(attb + 1048576);          // 4 MB f32 [16,256,256]
  short* st1   = (short*)(Zf + 1048576);            // [512][256] bf16: [M; Wg]
  short* st2   = st1 + 131072;                      // [512][256] bf16: [Wth; Wg]
  float* bias1 = (float*)(st2 + 131072);            // [512]: [0; bg]
  float* bias2 = bias1 + 512;                       // [512]: [bth; bg]
  float* vfull = bias2 + 512;                       // [16,9216]
  float* rbuf  = vfull + 147456;                    // [16,96]
  float* wv    = rbuf + 1536;                       // [256]
  float* tbar  = wv + 256;                          // [16,256]

  dim3 blk(256);

  // ---- precompute: st1 rows 0-255 = M = Wtheta^T * Wphi (bf16); stacks; wv ----
  gemm_k<1,1,1,1,1><<<dim3(4,4,1), blk, 0, stream>>>(wth, wph, st1, nullptr, nullptr, nullptr, nullptr,
      256, 256, 256, 256, 256, 256, 0, 0, 0, 1, 1, 0, 0);
  fill_k<<<512, blk, 0, stream>>>(wth, wg, bth, bg, st1, st2, bias1, bias2);
  wv_k<<<1, blk, 0, stream>>>(wph, bth, wv);

  // ================= pass 0 (width), pass 1 (height) =================
  for (int pass = 0; pass < 2; ++pass) {
    const float* xs = (pass == 0) ? xin : (const float*)x;
    // [Y; G] = [M; Wg] * x (+[0; bg]) -> bigY rows<256, bigG rows>=256  (x streamed ONCE)
    // grid: x=N-tiles (144) fastest, y=M-tiles -> same-B-panel blocks 144 apart (same XCD L2)
    if (fused) {
      gemm_k<0,1,1,0,1><<<dim3(144,8,16), blk, 0, stream>>>(st1, xs, bigY, bigG, bias1, nullptr, nullptr,
          512, 9216, 256, 256, 9216, 9216, 0, BS, BS, 1, 1, 256, 0);
    } else {
      gemm_k<0,1,1,0,1><<<dim3(144,4,16), blk, 0, stream>>>(st1, xs, bigY, nullptr, nullptr, nullptr, nullptr,
          256, 9216, 256, 256, 9216, 9216, 0, BS, BS, 1, 1, 0, 0);
    }
    // column bias r[b][j]
    vfull_k<<<576, blk, 0, stream>>>(xs, wv, vfull);
    rsum_k<<<6, blk, 0, stream>>>(vfull, rbuf, pass);
    // QK: logits[i][j] = sum_{(c,axis)} x(k,i) * Y(k,j)   (split-K 16)
    hipMemsetAsync(attf, 0, (size_t)16 * 9216 * sizeof(float), stream);
    if (pass == 0)
      gemm_k<1,1,0,1,0><<<dim3(2,2,256), blk, 0, stream>>>(xs, bigY, attf, nullptr, nullptr, nullptr, nullptr,
          96, 96, 24576, 96, 96, 96, BS, BS, 9216, 16, 1, 0, 0);
    else
      gemm_k<2,2,0,1,0><<<dim3(2,2,256), blk, 0, stream>>>(xs, bigY, attf, nullptr, nullptr, nullptr, nullptr,
          96, 96, 24576, 0, 0, 96, BS, BS, 9216, 16, 1, 0, 0);
    softmax_k<<<384, blk, 0, stream>>>(attf, attb, 96, 1536, rbuf, nullptr, nullptr);
    // fallback: G = Wg*x + bg separately (overwrites Y, now dead)
    if (!fused) {
      gemm_k<0,1,1,0,1><<<dim3(144,4,16), blk, 0, stream>>>(st1 + 65536, xs, bigG, nullptr, bias1 + 256,
          nullptr, nullptr, 256, 9216, 256, 256, 9216, 9216, 0, BS, BS, 1, 1, 0, 0);
    }
    // PV fused residual
    if (pass == 0)
      // x[b*BS + m*96 + n] = xin[...] + beta_w * sum_k G[m,k] att[n,k]  (full overwrite, no memcpy)
      gemm_k<0,0,5,0,0><<<dim3(2,384,16), blk, 0, stream>>>(bigG, attb, x, nullptr, nullptr, beta_w, xin,
          24576, 96, 96, 96, 96, 96, BS, 9216, BS, 1, 1, 0, 0);
    else
      // batched over (b,c): x += beta_h * att_b * G_{b,c}
      gemm_k<0,1,4,0,0><<<dim3(2,2,4096), blk, 0, stream>>>(attb, bigG, x, nullptr, nullptr, beta_h, nullptr,
          96, 96, 96, 96, 96, 96, 9216, 9216, 9216, 1, 256, 0, 0);
  }

  // ================= pass 2 (channel) =================
  // [Theta; G] = [Wth; Wg] * x + [bth; bg]
  if (fused) {
    gemm_k<0,1,1,0,1><<<dim3(144,8,16), blk, 0, stream>>>(st2, x, bigY, bigG, bias2, nullptr, nullptr,
        512, 9216, 256, 256, 9216, 9216, 0, BS, BS, 1, 1, 256, 0);
  } else {
    gemm_k<0,1,1,0,1><<<dim3(144,4,16), blk, 0, stream>>>(st2, x, bigY, nullptr, bias2, nullptr, nullptr,
        256, 9216, 256, 256, 9216, 9216, 0, BS, BS, 1, 1, 0, 0);
  }
  // Z[i][c] = sum_hw Theta[i,hw] * x[c,hw] (split-K 4)
  hipMemsetAsync(Zf, 0, (size_t)16 * 256 * 256 * sizeof(float), stream);
  gemm_k<0,0,0,0,1><<<dim3(4,4,64), blk, 0, stream>>>(bigY, x, Zf, nullptr, nullptr, nullptr, nullptr,
      256, 256, 9216, 9216, 9216, 256, BS, BS, 65536, 4, 1, 0, 0);
  // tbar[b][i] = sum_hw Theta[i,hw]
  sum_rows_k<<<1024, blk, 0, stream>>>(bigY, tbar, 9216, 4096);
  // L = Z * Wphi^T
  hipMemsetAsync(attf, 0, (size_t)16 * 256 * 256 * sizeof(float), stream);
  gemm_k<0,0,0,1,1><<<dim3(4,4,16), blk, 0, stream>>>(Zf, wph, attf, nullptr, nullptr, nullptr, nullptr,
      256, 256, 256, 256, 256, 256, 65536, 0, 65536, 1, 1, 0, 0);
  // softmax with rank-1 term tbar[row]*bphi[col]
  softmax_k<<<1024, blk, 0, stream>>>(attf, attb, 256, 4096, nullptr, tbar, bph);
  // fallback: G separately (overwrites Theta, now dead)
  if (!fused) {
    gemm_k<0,1,1,0,1><<<dim3(144,4,16), blk, 0, stream>>>(st1 + 65536, x, bigG, nullptr, bias1 + 256,
        nullptr, nullptr, 256, 9216, 256, 256, 9216, 9216, 0, BS, BS, 1, 1, 0, 0);
  }
  // PV: x[i,hw] += beta_c * sum_j att[i,j] G[j,hw]
  gemm_k<0,1,4,0,0><<<dim3(144,4,16), blk, 0, stream>>>(attb, bigG, x, nullptr, nullptr, beta_c, nullptr,
      256, 9216, 256, 256, 9216, 9216, 65536, BS, BS, 1, 1, 0, 0);
}